// Round 3
// baseline (245.458 us; speedup 1.0000x reference)
//
#include <hip/hip_runtime.h>
#include <math.h>

#define TPB   512
#define CAP   2048   // candidate list capacity (8 KiB LDS)
#define RPB   8      // rows per block (pipelined)
#define SRANK 96     // sample rank among 1024 samples -> E[candidates]~1535, sigma~150

// ---------------- boost precompute: boost = f32(exp(f64(1.5f*(0.02f - dc)))) ----
__global__ void boost_kernel(const float* __restrict__ dc, float* __restrict__ boost, int n) {
    int i = blockIdx.x * blockDim.x + threadIdx.x;
    if (i < n) {
        float a = 1.5f * (0.02f - dc[i]);   // exact f32 arithmetic, same as reference
        boost[i] = (float)exp((double)a);   // correctly-rounded f32 exp via f64
    }
}

// monotone float -> uint32 key (no NaNs in input)
__device__ __forceinline__ unsigned fkey(float f) {
    unsigned u = __float_as_uint(f);
    return (u & 0x80000000u) ? ~u : (u | 0x80000000u);
}

// wave-wide sum of per-lane count c (0..63) via bit-plane ballots; result uniform.
// Independent v_cmp -> s_bcnt1 pairs, no shfl dependency chain.
__device__ __forceinline__ int wave_sum6(int c) {
    int t;
    t  = (int)__popcll(__ballot(c & 1));
    t += (int)__popcll(__ballot(c & 2))  << 1;
    t += (int)__popcll(__ballot(c & 4))  << 2;
    t += (int)__popcll(__ballot(c & 8))  << 3;
    t += (int)__popcll(__ballot(c & 16)) << 4;
    t += (int)__popcll(__ballot(c & 32)) << 5;
    return t;
}

template<bool USE_B>
__global__ __launch_bounds__(TPB, 4)
void kwta_kernel(const float* __restrict__ x,
                 const float* __restrict__ boost,
                 const float* __restrict__ dc,
                 float* __restrict__ out,
                 int n, int k, int rows, int rpb) {
    const int tid  = threadIdx.x;
    const int lane = tid & 63;
    const int row0 = blockIdx.x * rpb;
    if (row0 >= rows) return;

    __shared__ unsigned s_list[CAP];
    __shared__ int s_cnt[4];
    __shared__ int s_nc;
    __shared__ unsigned s_bc[2];

    float4   xr[8];     // raw x staging (current, then prefetched next row)
    unsigned key[32];   // current row's keys

    auto load_row = [&](int row) {
        const float4* x4 = (const float4*)(x + (size_t)row * n);
        #pragma unroll
        for (int i = 0; i < 8; ++i) xr[i] = x4[tid + i * TPB];
    };

    auto build_keys = [&]() {
        if (USE_B) {
            const float4* b4 = (const float4*)boost;
            #pragma unroll
            for (int i = 0; i < 8; ++i) {
                float4 bv = b4[tid + i * TPB];
                key[4*i+0] = fkey(xr[i].x * bv.x);
                key[4*i+1] = fkey(xr[i].y * bv.y);
                key[4*i+2] = fkey(xr[i].z * bv.z);
                key[4*i+3] = fkey(xr[i].w * bv.w);
            }
        } else {
            const float4* d4 = (const float4*)dc;
            #pragma unroll
            for (int i = 0; i < 8; ++i) {
                float4 dv = d4[tid + i * TPB];
                key[4*i+0] = fkey(xr[i].x * (float)exp((double)(1.5f * (0.02f - dv.x))));
                key[4*i+1] = fkey(xr[i].y * (float)exp((double)(1.5f * (0.02f - dv.y))));
                key[4*i+2] = fkey(xr[i].z * (float)exp((double)(1.5f * (0.02f - dv.z))));
                key[4*i+3] = fkey(xr[i].w * (float)exp((double)(1.5f * (0.02f - dv.w))));
            }
        }
    };

    // prologue: first row (no overlap available)
    load_row(row0);
    build_keys();

    for (int r = 0; r < rpb; ++r) {
        const int row = row0 + r;
        if (row >= rows) break;

        if (tid < 4) s_cnt[tid] = 0;
        if (tid == 0) s_nc = 0;
        s_list[tid]       = key[5];    // 1024 samples, columns spread across the row
        s_list[tid + TPB] = key[21];
        __syncthreads();                           // (a) samples + resets visible

        // ---- wave 0: 16-bit bisection on 1024 samples -> conservative pivot Tlo ----
        if (tid < 64) {
            unsigned samp[16];
            #pragma unroll
            for (int j = 0; j < 16; ++j) samp[j] = s_list[lane + j * 64];
            unsigned T = 0;
            #pragma unroll
            for (int b = 31; b >= 16; --b) {
                unsigned C = T | (1u << b);
                int c = 0;
                #pragma unroll
                for (int j = 0; j < 16; ++j) c += (samp[j] >= C) ? 1 : 0;
                if (wave_sum6(c) >= SRANK) T = C;  // uniform
            }
            if (lane == 0) s_bc[0] = T;
        }
        __syncthreads();                           // (b)
        const unsigned Tlo = s_bc[0];

        // ---- compact candidates (key >= Tlo) into LDS via wave-aggregated append ----
        #pragma unroll
        for (int j = 0; j < 32; ++j) {
            bool e = (key[j] >= Tlo);
            unsigned long long m = __ballot(e);
            if (m) {
                int cntm   = (int)__popcll(m);
                int pre    = (int)__popcll(m & ((1ull << lane) - 1ull));
                int leader = __ffsll((long long)m) - 1;
                int base = 0;
                if (lane == leader) base = atomicAdd(&s_nc, cntm);
                base = __shfl(base, leader);
                if (e) {
                    int pos = base + pre;
                    if (pos < CAP) s_list[pos] = key[j];
                }
            }
        }
        __syncthreads();                           // (c)
        const int nc = s_nc;

        // ---- prefetch next row; latency hides under the final bisect ----
        const bool pf = (r + 1 < rpb) && (row + 1 < rows);
        if (pf) load_row(row + 1);

        unsigned P;
        if (nc >= k && nc <= CAP) {
            // fast path: wave 0 exact 32-bit bisection over candidates at rank k
            if (tid < 64) {
                unsigned cand[32];
                #pragma unroll
                for (int j = 0; j < 32; ++j) {
                    int idx = lane + j * 64;
                    cand[j] = (idx < nc) ? s_list[idx] : 0u;  // key 0 never counts
                }
                unsigned Q = 0;
                for (int b = 31; b >= 0; --b) {
                    unsigned C = Q | (1u << b);
                    int c = 0;
                    #pragma unroll
                    for (int j = 0; j < 32; ++j) c += (cand[j] >= C) ? 1 : 0;
                    if (wave_sum6(c) >= k) Q = C;
                }
                if (lane == 0) s_bc[1] = Q;
            }
            __syncthreads();                       // (d)
            P = s_bc[1];
        } else {
            // fallback: full block-wide bisection (correct for any data; ~never taken)
            int it = 0;
            auto block_total = [&](int c) -> int {
                #pragma unroll
                for (int off = 32; off; off >>= 1) c += __shfl_down(c, off);
                int s = it & 3;
                if (lane == 0) atomicAdd(&s_cnt[s], c);
                __syncthreads();
                int total = s_cnt[s];
                if (tid == 0) s_cnt[(s + 2) & 3] = 0;
                ++it;
                return total;
            };
            P = 0;
            for (int b = 31; b >= 0; --b) {
                unsigned C = P | (1u << b);
                int c = 0;
                #pragma unroll
                for (int j = 0; j < 32; ++j) c += (key[j] >= C) ? 1 : 0;
                if (block_total(c) >= k) P = C;
            }
        }

        // ---- write mask (key >= P  <=>  xb >= threshold) ----
        float4* o4 = (float4*)(out + (size_t)row * n);
        #pragma unroll
        for (int i = 0; i < 8; ++i) {
            float4 o;
            o.x = (key[4*i+0] >= P) ? 1.0f : 0.0f;
            o.y = (key[4*i+1] >= P) ? 1.0f : 0.0f;
            o.z = (key[4*i+2] >= P) ? 1.0f : 0.0f;
            o.w = (key[4*i+3] >= P) ? 1.0f : 0.0f;
            o4[tid + i * TPB] = o;
        }

        // ---- build keys for next row from the prefetched data ----
        if (pf) build_keys();
    }
}

extern "C" void kernel_launch(void* const* d_in, const int* in_sizes, int n_in,
                              void* d_out, int out_size, void* d_ws, size_t ws_size,
                              hipStream_t stream) {
    const float* x  = (const float*)d_in[0];
    const float* dc = (const float*)d_in[1];
    float* out = (float*)d_out;

    int n    = in_sizes[1];             // 16384
    int rows = in_sizes[0] / n;         // 4096
    int k    = (int)llround((double)n * 0.02);
    if (k < 1) k = 1;

    int rpb  = RPB;
    int nblk = (rows + rpb - 1) / rpb;

    bool use_ws = (ws_size >= (size_t)n * sizeof(float));
    if (use_ws) {
        float* boost = (float*)d_ws;
        boost_kernel<<<(n + 255) / 256, 256, 0, stream>>>(dc, boost, n);
        kwta_kernel<true><<<nblk, TPB, 0, stream>>>(x, boost, dc, out, n, k, rows, rpb);
    } else {
        kwta_kernel<false><<<nblk, TPB, 0, stream>>>(x, nullptr, dc, out, n, k, rows, rpb);
    }
}

// Round 4
// 186.866 us; speedup vs baseline: 1.3136x; 1.3136x over previous
//
#include <hip/hip_runtime.h>
#include <math.h>
#include <string.h>

#define TPB   1024
#define KPT   16          // keys per thread (n = TPB*KPT = 16384)
#define CAP   2048        // candidate list capacity (8 KiB LDS)
#define WAVES (TPB/64)

// ---------------- boost precompute: boost = f32(exp(f64(1.5f*(0.02f - dc)))) ----
__global__ void boost_kernel(const float* __restrict__ dc, float* __restrict__ boost, int n) {
    int i = blockIdx.x * blockDim.x + threadIdx.x;
    if (i < n) {
        float a = 1.5f * (0.02f - dc[i]);   // exact f32 arithmetic, same as reference
        boost[i] = (float)exp((double)a);   // correctly-rounded f32 exp via f64
    }
}

// monotone float -> uint32 key (no NaNs in input)
__device__ __forceinline__ unsigned fkey(float f) {
    unsigned u = __float_as_uint(f);
    return (u & 0x80000000u) ? ~u : (u | 0x80000000u);
}

// wave-wide sum of per-lane count c (0..63) via bit-plane ballots; uniform result.
__device__ __forceinline__ int wave_sum6(int c) {
    int t;
    t  = (int)__popcll(__ballot(c & 1));
    t += (int)__popcll(__ballot(c & 2))  << 1;
    t += (int)__popcll(__ballot(c & 4))  << 2;
    t += (int)__popcll(__ballot(c & 8))  << 3;
    t += (int)__popcll(__ballot(c & 16)) << 4;
    t += (int)__popcll(__ballot(c & 32)) << 5;
    return t;
}

template<bool USE_B>
__global__ __launch_bounds__(TPB, 8)   // <=64 VGPR target -> 2 blocks/CU, no spill
void kwta_kernel(const float* __restrict__ x,
                 const float* __restrict__ boost,
                 const float* __restrict__ dc,
                 float* __restrict__ out,
                 int n, int k, unsigned PIV) {
    const int tid  = threadIdx.x;
    const int lane = tid & 63;
    const int wave = tid >> 6;
    const int row  = blockIdx.x;

    __shared__ unsigned s_list[CAP];
    __shared__ int s_cnt[4];
    __shared__ int s_nc;
    __shared__ unsigned s_P;

    if (tid == 0) s_nc = 0;
    if (tid < 4) s_cnt[tid] = 0;

    // ---- load row, build 16 keys/thread in registers ----
    const float4* x4 = (const float4*)(x + (size_t)row * n);
    unsigned key[KPT];
    if (USE_B) {
        const float4* b4 = (const float4*)boost;
        #pragma unroll
        for (int i = 0; i < KPT/4; ++i) {
            float4 xv = x4[tid + i * TPB];
            float4 bv = b4[tid + i * TPB];
            key[4*i+0] = fkey(xv.x * bv.x);
            key[4*i+1] = fkey(xv.y * bv.y);
            key[4*i+2] = fkey(xv.z * bv.z);
            key[4*i+3] = fkey(xv.w * bv.w);
        }
    } else {
        const float4* d4 = (const float4*)dc;
        #pragma unroll
        for (int i = 0; i < KPT/4; ++i) {
            float4 xv = x4[tid + i * TPB];
            float4 dv = d4[tid + i * TPB];
            key[4*i+0] = fkey(xv.x * (float)exp((double)(1.5f * (0.02f - dv.x))));
            key[4*i+1] = fkey(xv.y * (float)exp((double)(1.5f * (0.02f - dv.y))));
            key[4*i+2] = fkey(xv.z * (float)exp((double)(1.5f * (0.02f - dv.z))));
            key[4*i+3] = fkey(xv.w * (float)exp((double)(1.5f * (0.02f - dv.w))));
        }
    }
    __syncthreads();                         // (a) s_nc/s_cnt resets visible

    // ---- compact candidates (key >= PIV) into LDS via wave-aggregated append ----
    #pragma unroll
    for (int j = 0; j < KPT; ++j) {
        bool e = (key[j] >= PIV);
        unsigned long long m = __ballot(e);
        if (m) {
            int cntm   = (int)__popcll(m);
            int pre    = (int)__popcll(m & ((1ull << lane) - 1ull));
            int leader = __ffsll((long long)m) - 1;
            int base = 0;
            if (lane == leader) base = atomicAdd(&s_nc, cntm);
            base = __shfl(base, leader);
            if (e) {
                int pos = base + pre;
                if (pos < CAP) s_list[pos] = key[j];
            }
        }
    }
    __syncthreads();                         // (b) candidates + nc visible
    const int nc = s_nc;

    unsigned P;
    if (nc >= k && nc <= CAP) {
        // fast path: one wave (SIMD-spread by row) exact bisect, 2 bits/round.
        // Counting among candidates == global count for any probe when nc >= k.
        if (wave == (row & (WAVES - 1))) {
            const int mrd = (nc + 63) >> 6;   // LDS reads per lane (<=32)
            unsigned Q = 0;
            for (int b = 30; b >= 0; b -= 2) {
                const unsigned CA = Q | (1u << (b + 1));
                const unsigned CB = Q | (1u << b);
                const unsigned CC = CA | (1u << b);
                int ca = 0, cb = 0, cc = 0;
                for (int j = 0; j < mrd; ++j) {
                    const int idx = lane + (j << 6);
                    const unsigned v = (idx < nc) ? s_list[idx] : 0u;  // 0 never >= probe
                    ca += (v >= CA) ? 1 : 0;
                    cb += (v >= CB) ? 1 : 0;
                    cc += (v >= CC) ? 1 : 0;
                }
                const int A = wave_sum6(ca);
                const int B = wave_sum6(cb);
                const int C = wave_sum6(cc);
                if (A >= k)      Q = (C >= k) ? CC : CA;
                else if (B >= k) Q = CB;
            }
            if (lane == 0) s_P = Q;
        }
        __syncthreads();                     // (c) P published
        P = s_P;
    } else {
        // fallback: block-wide 32-round bisect (exact for ANY data; ~never taken)
        int it = 0;
        P = 0;
        for (int b = 31; b >= 0; --b) {
            const unsigned C = P | (1u << b);
            int c = 0;
            #pragma unroll
            for (int j = 0; j < KPT; ++j) c += (key[j] >= C) ? 1 : 0;
            int t = wave_sum6(c);
            const int s = it & 3;
            if (lane == 0) atomicAdd(&s_cnt[s], t);
            __syncthreads();
            const int total = s_cnt[s];
            if (tid == 0) s_cnt[(s + 2) & 3] = 0;
            ++it;
            if (total >= k) P = C;
        }
    }

    // ---- write mask (key >= P  <=>  xb >= threshold) ----
    float4* o4 = (float4*)(out + (size_t)row * n);
    #pragma unroll
    for (int i = 0; i < KPT/4; ++i) {
        float4 o;
        o.x = (key[4*i+0] >= P) ? 1.0f : 0.0f;
        o.y = (key[4*i+1] >= P) ? 1.0f : 0.0f;
        o.z = (key[4*i+2] >= P) ? 1.0f : 0.0f;
        o.w = (key[4*i+3] >= P) ? 1.0f : 0.0f;
        o4[tid + i * TPB] = o;
    }
}

extern "C" void kernel_launch(void* const* d_in, const int* in_sizes, int n_in,
                              void* d_out, int out_size, void* d_ws, size_t ws_size,
                              hipStream_t stream) {
    const float* x  = (const float*)d_in[0];
    const float* dc = (const float*)d_in[1];
    float* out = (float*)d_out;

    int n    = in_sizes[1];             // 16384
    int rows = in_sizes[0] / n;         // 4096
    int k    = (int)llround((double)n * 0.02);
    if (k < 1) k = 1;

    // fixed conservative pivot: xb >= 1.15 -> ~500 candidates/row on this data;
    // block-wide fallback guarantees correctness for any data.
    float pivf = 1.15f;
    unsigned pu;
    memcpy(&pu, &pivf, sizeof(pu));
    unsigned PIV = (pu & 0x80000000u) ? ~pu : (pu | 0x80000000u);

    bool use_ws = (ws_size >= (size_t)n * sizeof(float));
    if (use_ws) {
        float* boost = (float*)d_ws;
        boost_kernel<<<(n + 255) / 256, 256, 0, stream>>>(dc, boost, n);
        kwta_kernel<true><<<rows, TPB, 0, stream>>>(x, boost, dc, out, n, k, PIV);
    } else {
        kwta_kernel<false><<<rows, TPB, 0, stream>>>(x, nullptr, dc, out, n, k, PIV);
    }
}